// Round 3
// baseline (54.210 us; speedup 1.0000x reference)
//
#include <hip/hip_runtime.h>

// Problem constants (from reference): B=8, N=64, I=128, H=1024
#define BB 8
#define NN 64
#define II 128
#define HH 1024
#define TOTAL_OUT (BB * NN * II)   // 65536

// Kernel 1: v[b][j] = sum_k W[j][k] * hidden[b][k]
// One 256-thread block per j: the whole H=1024 dot is covered in a SINGLE
// round of loads (1 W float4 + 8 hidden float4 per thread, all independent),
// so only one HBM latency exposure. Then wave shuffle-reduce + LDS cross-wave.
__global__ void compute_v_kernel(const float* __restrict__ W,
                                 const float* __restrict__ hidden,
                                 float* __restrict__ v) {
    int j    = blockIdx.x;          // 0..1023
    int t    = threadIdx.x;         // 0..255
    int lane = t & 63;
    int w    = t >> 6;              // wave 0..3

    const float4* Wrow = reinterpret_cast<const float4*>(W + (size_t)j * HH);
    const float4* Hv   = reinterpret_cast<const float4*>(hidden);

    float4 w4 = Wrow[t];            // 256 float4 = full row
    float acc[BB];
#pragma unroll
    for (int b = 0; b < BB; ++b) {
        float4 h4 = Hv[b * (HH / 4) + t];
        acc[b] = w4.x * h4.x + w4.y * h4.y + w4.z * h4.z + w4.w * h4.w;
    }

#pragma unroll
    for (int b = 0; b < BB; ++b) {
#pragma unroll
        for (int off = 32; off > 0; off >>= 1)
            acc[b] += __shfl_xor(acc[b], off, 64);
    }

    __shared__ float part[4][BB];
    if (lane == 0) {
#pragma unroll
        for (int b = 0; b < BB; ++b) part[w][b] = acc[b];
    }
    __syncthreads();
    if (t < BB) {
        float s = part[0][t] + part[1][t] + part[2][t] + part[3][t];
        v[t * HH + j] = s;          // v[b][j]
    }
}

// Kernel 2: out[o] = dot(enc[o, :], v[b, :]) + bias.
// One wave per FOUR consecutive output rows: 16 independent enc float4 loads
// in flight per iteration, v row amortized over 4 rows, float4 output store.
__global__ void bilinear_out_kernel(const float* __restrict__ enc,
                                    const float* __restrict__ v,
                                    const float* __restrict__ bias,
                                    float* __restrict__ out) {
    int wave = (blockIdx.x * blockDim.x + threadIdx.x) >> 6;
    int lane = threadIdx.x & 63;
    int o0 = wave * 4;
    if (o0 >= TOTAL_OUT) return;
    int b = o0 >> 13;                               // N*I = 8192 = 2^13
    // 8192 rows per b, o0 multiple of 4 -> all 4 rows share b.

    const float4* e0 = reinterpret_cast<const float4*>(enc) + (size_t)o0 * (HH / 4);
    const float4* vr = reinterpret_cast<const float4*>(v) + (size_t)b * (HH / 4);

    float a0 = 0.f, a1 = 0.f, a2 = 0.f, a3 = 0.f;
#pragma unroll
    for (int it = 0; it < HH / 256; ++it) {         // 4 iterations
        float4 vv = vr[it * 64 + lane];
        float4 x0 = e0[          it * 64 + lane];
        float4 x1 = e0[256     + it * 64 + lane];
        float4 x2 = e0[512     + it * 64 + lane];
        float4 x3 = e0[768     + it * 64 + lane];
        a0 += x0.x * vv.x + x0.y * vv.y + x0.z * vv.z + x0.w * vv.w;
        a1 += x1.x * vv.x + x1.y * vv.y + x1.z * vv.z + x1.w * vv.w;
        a2 += x2.x * vv.x + x2.y * vv.y + x2.z * vv.z + x2.w * vv.w;
        a3 += x3.x * vv.x + x3.y * vv.y + x3.z * vv.z + x3.w * vv.w;
    }

#pragma unroll
    for (int off = 32; off > 0; off >>= 1) {
        a0 += __shfl_xor(a0, off, 64);
        a1 += __shfl_xor(a1, off, 64);
        a2 += __shfl_xor(a2, off, 64);
        a3 += __shfl_xor(a3, off, 64);
    }
    if (lane == 0) {
        float bb = bias[0];
        float4 r = make_float4(a0 + bb, a1 + bb, a2 + bb, a3 + bb);
        *reinterpret_cast<float4*>(out + o0) = r;
    }
}

extern "C" void kernel_launch(void* const* d_in, const int* in_sizes, int n_in,
                              void* d_out, int out_size, void* d_ws, size_t ws_size,
                              hipStream_t stream) {
    const float* hidden = (const float*)d_in[0];   // [B, H]
    const float* enc    = (const float*)d_in[1];   // [B, N, I, H]
    // d_in[2] = input_lengths (unused by the math)
    const float* W      = (const float*)d_in[3];   // [H, H]
    const float* bias   = (const float*)d_in[4];   // [1]
    float* out = (float*)d_out;                    // [B, N, I] f32
    float* v   = (float*)d_ws;                     // [B, H] scratch = 32 KB

    // Kernel 1: one block per j -> 1024 blocks x 256 threads
    compute_v_kernel<<<HH, 256, 0, stream>>>(W, hidden, v);

    // Kernel 2: 16384 waves (4 rows each) -> 4096 blocks x 256 threads
    bilinear_out_kernel<<<(TOTAL_OUT / 4 * 64) / 256, 256, 0, stream>>>(enc, v, bias, out);
}